// Round 7
// baseline (152.236 us; speedup 1.0000x reference)
//
#include <hip/hip_runtime.h>
#include <hip/hip_bf16.h>

// Problem constants (from reference)
#define N_PARENT 16384
#define N_CHILD (8 * N_PARENT)   // 131072
#define CC 128                   // channels
#define KK 27                    // stencil taps

// GEMM tiling: 128x128 block tile, 4 waves (2x2), 64x64 per wave, BK=32.
// BK=32 (64-B LDS rows) makes the b128 frag-read pattern bank-uniform
// (odd/even rows hit disjoint bank halves) -> NO swizzle needed.
// LDS = 2x8K(A) + 2x8K(B) + 6.75K(ridx) = 39.7 KB -> 4 blocks/CU.
#define BM 128
#define BN 128
#define BK 32

// ws layout (bf16 element offsets)
#define XB_OFF 0
#define XB_ELEMS (N_PARENT * CC)             // 2,097,152
#define WT_OFF XB_ELEMS
#define WT_ELEMS (KK * CC * CC)              // 442,368
#define ZR_OFF (WT_OFF + WT_ELEMS)
#define ZR_ELEMS 128
#define ZR_ROW 19840                         // ZR_OFF*2/256: zero row's 256-B row idx

typedef __attribute__((ext_vector_type(8))) __bf16 bf16x8;
typedef __attribute__((ext_vector_type(4))) float f32x4;

__device__ __forceinline__ void gll16(const void* g, void* l) {
  __builtin_amdgcn_global_load_lds(
      (const __attribute__((address_space(1))) unsigned int*)g,
      (__attribute__((address_space(3))) unsigned int*)l,
      16, 0, 0);
}

// Cast x to bf16, build w^T[k][d][c] in bf16, zero row.
__global__ void prep_kernel(const float* __restrict__ x,
                            const float* __restrict__ w,
                            __hip_bfloat16* __restrict__ ws) {
  const int stride = gridDim.x * blockDim.x;
  const int tid = blockIdx.x * blockDim.x + threadIdx.x;
  for (int i = tid; i < XB_ELEMS; i += stride)
    ws[XB_OFF + i] = __float2bfloat16(x[i]);
  for (int j = tid; j < WT_ELEMS; j += stride) {
    const int k = j / (CC * CC);
    const int rem = j - k * CC * CC;
    const int d = rem >> 7;   // output channel
    const int c = rem & 127;  // input channel
    ws[WT_OFF + j] = __float2bfloat16(w[k * CC * CC + c * CC + d]);
  }
  if (tid < ZR_ELEMS) ws[ZR_OFF + tid] = __float2bfloat16(0.0f);
}

// Structure: R6's counted-vmcnt dbuf, 108 sub-stages (27 taps x 4 c-quarters).
// Per sub-stage: issue next batch (4 gll16), vmcnt(4), bar, compute
// (8 ds_read_b128 + 16 MFMA), bar. 4 blocks/CU provide cross-block pipe
// overlap (m97 mechanism) without relying on intra-block scheduling.
__global__ __launch_bounds__(256, 4) void upconv_kernel(
    const int* __restrict__ neigh,
    const __hip_bfloat16* __restrict__ ws,
    const float* __restrict__ bias,
    float* __restrict__ out) {
  __shared__ __align__(16) __hip_bfloat16 As[2][BM * BK];  // 16 KB
  __shared__ __align__(16) __hip_bfloat16 Bs[2][BN * BK];  // 16 KB
  __shared__ unsigned short ridx[BM * KK];                 // 6.75 KB

  const int tid = threadIdx.x;
  const int wv = tid >> 6;   // wave 0..3
  const int l = tid & 63;    // lane
  const int wr = wv >> 1;    // wave row (64-row strip)
  const int wc = wv & 1;     // wave col (64-col strip)
  const int row0 = blockIdx.x * BM;

  // Preload neighbor row indices (coalesced) as 256-B-row indices.
  for (int j = tid; j < BM * KK; j += 256) {
    const int nv = neigh[row0 * KK + j];
    ridx[j] = (unsigned short)((nv >= 0) ? (nv >> 3) : ZR_ROW);
  }
  __syncthreads();

  const int lr = l & 15;          // frag row within 16
  const int lk8 = (l >> 4) * 8;   // frag chunk offset (elements, 0..24)
  const int g16 = l >> 2;         // staging: row within 16-row group
  const int lbA = (l & 3) * 16;   // staging: byte within 64-B quarter-row
  const int sB = g16 * 256 + lbA; // staging: B per-lane byte offset

  const char* xbB = (const char*)(ws + XB_OFF);
  const char* wp = (const char*)(ws + WT_OFF);  // advances 32 KB per tap

  f32x4 acc[4][4] = {};

  // Per-tap A staging byte offsets (2 x 16-row groups per wave).
  const int ri0 = (wv * 32 + g16) * KK;        // ridx index, group 0
  const int ri1 = (wv * 32 + 16 + g16) * KK;   // group 1
  int r0 = ((int)ridx[ri0]) << 8;
  int r1 = ((int)ridx[ri1]) << 8;

  // --- staging: 4 gll16(16B->1KB)/wave/sub-stage (2 A + 2 B) --------------
  auto stageA = [&](int buf, int qb, int a0, int a1) {
    gll16(xbB + a0 + qb + lbA, &As[buf][(wv * 32) * BK]);
    gll16(xbB + a1 + qb + lbA, &As[buf][(wv * 32 + 16) * BK]);
  };
  auto stageB = [&](int buf, const char* w, int qb) {
    gll16(w + (wv * 32) * 256 + qb + sB, &Bs[buf][(wv * 32) * BK]);
    gll16(w + (wv * 32 + 16) * 256 + qb + sB, &Bs[buf][(wv * 32 + 16) * BK]);
  };

  // --- compute: 8 ds_read_b128 + 16 MFMA (one K=32 slice) -----------------
  auto compute = [&](int buf) {
    bf16x8 a[4], b[4];
#pragma unroll
    for (int m = 0; m < 4; ++m)
      a[m] = *reinterpret_cast<const bf16x8*>(
          &As[buf][(wr * 64 + m * 16 + lr) * BK + lk8]);
#pragma unroll
    for (int n = 0; n < 4; ++n)
      b[n] = *reinterpret_cast<const bf16x8*>(
          &Bs[buf][(wc * 64 + n * 16 + lr) * BK + lk8]);
    __builtin_amdgcn_s_setprio(1);
#pragma unroll
    for (int m = 0; m < 4; ++m)
#pragma unroll
      for (int n = 0; n < 4; ++n)
        acc[m][n] = __builtin_amdgcn_mfma_f32_16x16x32_bf16(
            a[m], b[n], acc[m][n], 0, 0, 0);
    __builtin_amdgcn_s_setprio(0);
  };

#define WAITN(n) asm volatile("s_waitcnt vmcnt(" #n ")" ::: "memory")
#define BAR() __builtin_amdgcn_s_barrier()

  // --- prologue: stage (tap0, q0) -> buf0 ---------------------------------
  stageB(0, wp, 0);
  stageA(0, 0, r0, r1);

  // --- main loop: 27 taps x 4 c-quarters (q offsets 0/64/128/192 bytes) ---
  for (int k = 0; k < KK; ++k) {
    // q0: issue (k,q1)->buf1
    stageB(1, wp, 64);
    stageA(1, 64, r0, r1);
    WAITN(4); BAR();
    compute(0);
    BAR();

    // q1: issue (k,q2)->buf0
    stageB(0, wp, 128);
    stageA(0, 128, r0, r1);
    WAITN(4); BAR();
    compute(1);
    BAR();

    // q2: issue (k,q3)->buf1 ; prefetch next tap's row offsets (lgkm)
    stageB(1, wp, 192);
    stageA(1, 192, r0, r1);
    int n0 = r0, n1 = r1;
    if (k + 1 < KK) {
      n0 = ((int)ridx[ri0 + k + 1]) << 8;
      n1 = ((int)ridx[ri1 + k + 1]) << 8;
    }
    WAITN(4); BAR();
    compute(0);
    BAR();

    // q3: issue (k+1,q0)->buf0
    wp += 2 * CC * CC;  // 32 KB per tap
    if (k + 1 < KK) {
      stageB(0, wp, 0);
      stageA(0, 0, n0, n1);
      WAITN(4);
    } else {
      WAITN(0);
    }
    BAR();
    compute(1);
    BAR();

    r0 = n0; r1 = n1;
  }

  // --- epilogue: C/D layout col=lane&15, row=(lane>>4)*4+q ---------------
  float bv[4];
#pragma unroll
  for (int n = 0; n < 4; ++n) bv[n] = bias[wc * 64 + n * 16 + lr];
  const int rbase = row0 + wr * 64 + (l >> 4) * 4;
#pragma unroll
  for (int m = 0; m < 4; ++m)
#pragma unroll
    for (int n = 0; n < 4; ++n)
#pragma unroll
      for (int q = 0; q < 4; ++q)
        out[(size_t)(rbase + m * 16 + q) * CC + wc * 64 + n * 16 + lr] =
            acc[m][n][q] + bv[n];
}

extern "C" void kernel_launch(void* const* d_in, const int* in_sizes, int n_in,
                              void* d_out, int out_size, void* d_ws,
                              size_t ws_size, hipStream_t stream) {
  const float* x = (const float*)d_in[0];
  const float* w = (const float*)d_in[1];
  const float* b = (const float*)d_in[2];
  const int* neigh = (const int*)d_in[3];
  __hip_bfloat16* ws = (__hip_bfloat16*)d_ws;
  float* out = (float*)d_out;

  hipLaunchKernelGGL(prep_kernel, dim3(512), dim3(256), 0, stream, x, w, ws);
  hipLaunchKernelGGL(upconv_kernel, dim3(N_CHILD / BM), dim3(256), 0, stream,
                     neigh, ws, b, out);
}

// Round 8
// 129.496 us; speedup vs baseline: 1.1756x; 1.1756x over previous
//
#include <hip/hip_runtime.h>
#include <hip/hip_bf16.h>

// Problem constants (from reference)
#define N_PARENT 16384
#define N_CHILD (8 * N_PARENT)   // 131072
#define CC 128                   // channels
#define KK 27                    // stencil taps

// GEMM tiling: 256x128 block tile, 4 waves (2Mx2N), wave tile 128x64
// (M_rep=8, N_rep=4 -> 43.7 FLOP per LDS byte vs 32 at 64x64), BK=32.
// LDS = 2x16K(A) + 2x8K(B) + 13.5K(ridx) = 61.5 KB -> 2 blocks/CU.
#define BM 256
#define BN 128
#define BK 32

// ws layout (bf16 element offsets)
#define XB_OFF 0
#define XB_ELEMS (N_PARENT * CC)             // 2,097,152
#define WT_OFF XB_ELEMS
#define WT_ELEMS (KK * CC * CC)              // 442,368
#define ZR_OFF (WT_OFF + WT_ELEMS)
#define ZR_ELEMS 128
#define ZR_ROW 19840                         // ZR_OFF*2/256: zero row idx (256-B rows)

typedef __attribute__((ext_vector_type(8))) __bf16 bf16x8;
typedef __attribute__((ext_vector_type(4))) float f32x4;

__device__ __forceinline__ void gll16(const void* g, void* l) {
  __builtin_amdgcn_global_load_lds(
      (const __attribute__((address_space(1))) unsigned int*)g,
      (__attribute__((address_space(3))) unsigned int*)l,
      16, 0, 0);
}

// Cast x to bf16, build w^T[k][d][c] in bf16, zero row.
__global__ void prep_kernel(const float* __restrict__ x,
                            const float* __restrict__ w,
                            __hip_bfloat16* __restrict__ ws) {
  const int stride = gridDim.x * blockDim.x;
  const int tid = blockIdx.x * blockDim.x + threadIdx.x;
  for (int i = tid; i < XB_ELEMS; i += stride)
    ws[XB_OFF + i] = __float2bfloat16(x[i]);
  for (int j = tid; j < WT_ELEMS; j += stride) {
    const int k = j / (CC * CC);
    const int rem = j - k * CC * CC;
    const int d = rem >> 7;   // output channel
    const int c = rem & 127;  // input channel
    ws[WT_OFF + j] = __float2bfloat16(w[k * CC * CC + c * CC + d]);
  }
  if (tid < ZR_ELEMS) ws[ZR_OFF + tid] = __float2bfloat16(0.0f);
}

// BK=32 swizzle (64-B LDS rows, 4 x 16-B chunks): phys_chunk = chunk ^
// ((row>>1)&3). Bank check, lanes 0-15 chunk0: banks {0,16,4,20,8,24,12,28},
// only row r / r+8 alias -> 2-way (free, m136). Applied both-sides:
// gll16 dest linear, source col = ((l&3)^((l>>3)&3))*16; frag-read chunk =
// (l>>4) ^ ((lr>>1)&3)  (row bits 1-2 == lr bits 1-2 since m*16 is bit4+).
// Sync: R6-proven counted-vmcnt dbuf, 6 vmem/stage, WAITN(6).
__global__ __launch_bounds__(256, 2) void upconv_kernel(
    const int* __restrict__ neigh,
    const __hip_bfloat16* __restrict__ ws,
    const float* __restrict__ bias,
    float* __restrict__ out) {
  __shared__ __align__(16) __hip_bfloat16 As[2][BM * BK];  // 2 x 16 KB
  __shared__ __align__(16) __hip_bfloat16 Bs[2][BN * BK];  // 2 x 8 KB
  __shared__ unsigned short ridx[BM * KK];                 // 13.5 KB

  const int tid = threadIdx.x;
  const int wv = tid >> 6;   // wave 0..3
  const int l = tid & 63;    // lane
  const int wr = wv >> 1;    // wave row (128-row strip)
  const int wc = wv & 1;     // wave col (64-col strip)
  const int row0 = blockIdx.x * BM;

  // Preload neighbor row indices (coalesced), as 256-B-row indices.
  for (int j = tid; j < BM * KK; j += 256) {
    const int nv = neigh[row0 * KK + j];
    ridx[j] = (unsigned short)((nv >= 0) ? (nv >> 3) : ZR_ROW);
  }
  __syncthreads();

  const int lr = l & 15;                      // frag row within 16
  const int coE = (((l >> 4) ^ ((lr >> 1) & 3)) * 8);  // frag chunk (elems)
  const int lch = ((l & 3) ^ ((l >> 3) & 3)) * 16;     // staging src col (bytes)

  const char* xbB = (const char*)(ws + XB_OFF);
  // Per-lane B staging base: d-row = wv*32 + (l>>2), w^T row stride 256 B.
  const char* wLane =
      (const char*)(ws + WT_OFF) + (wv * 32 + (l >> 2)) * 256 + lch;

  f32x4 acc[8][4] = {};

  // ridx indices for this lane's 4 A-staging groups (16 rows each).
  const int riB = (wv * 64 + (l >> 2)) * KK;
  int rr[4], nr[4];
#pragma unroll
  for (int i = 0; i < 4; ++i) rr[i] = ((int)ridx[riB + i * 16 * KK]) << 8;

  // --- staging: 6 gll16/wave/stage (4 A + 2 B) ----------------------------
  auto stageA = [&](int buf, int qb, const int* r) {
#pragma unroll
    for (int i = 0; i < 4; ++i)
      gll16(xbB + r[i] + qb + lch, &As[buf][(wv * 64 + i * 16) * BK]);
  };
  auto stageB = [&](int buf, int tqb) {  // tqb = tap*32768 + quarter byte
#pragma unroll
    for (int j = 0; j < 2; ++j)
      gll16(wLane + tqb + j * 4096, &Bs[buf][(wv * 32 + j * 16) * BK]);
  };

  // --- compute: 12 ds_read_b128 + 32 MFMA (one K=32 slice) ----------------
  auto compute = [&](int buf) {
    bf16x8 a[8], b[4];
#pragma unroll
    for (int m = 0; m < 8; ++m)
      a[m] = *reinterpret_cast<const bf16x8*>(
          &As[buf][(wr * 128 + m * 16 + lr) * BK + coE]);
#pragma unroll
    for (int n = 0; n < 4; ++n)
      b[n] = *reinterpret_cast<const bf16x8*>(
          &Bs[buf][(wc * 64 + n * 16 + lr) * BK + coE]);
    __builtin_amdgcn_s_setprio(1);
#pragma unroll
    for (int m = 0; m < 8; ++m)
#pragma unroll
      for (int n = 0; n < 4; ++n)
        acc[m][n] = __builtin_amdgcn_mfma_f32_16x16x32_bf16(
            a[m], b[n], acc[m][n], 0, 0, 0);
    __builtin_amdgcn_s_setprio(0);
  };

#define WAITN(n) asm volatile("s_waitcnt vmcnt(" #n ")" ::: "memory")
#define BAR() __builtin_amdgcn_s_barrier()

  // --- prologue: stage (tap0, q0) -> buf0 ---------------------------------
  stageB(0, 0);
  stageA(0, 0, rr);

  // --- main loop: 27 taps x 4 c-quarters ----------------------------------
  for (int k = 0; k < KK; ++k) {
    const int tb = k * 32768;  // B tap byte offset (2*CC*CC bytes)

    // q0: issue (k,q1)->buf1
    stageB(1, tb + 64);
    stageA(1, 64, rr);
    WAITN(6); BAR();
    compute(0);
    BAR();

    // q1: issue (k,q2)->buf0
    stageB(0, tb + 128);
    stageA(0, 128, rr);
    WAITN(6); BAR();
    compute(1);
    BAR();

    // q2: issue (k,q3)->buf1 ; prefetch next tap's row offsets (lgkm)
    stageB(1, tb + 192);
    stageA(1, 192, rr);
#pragma unroll
    for (int i = 0; i < 4; ++i)
      nr[i] = (k + 1 < KK) ? (((int)ridx[riB + i * 16 * KK + k + 1]) << 8)
                           : rr[i];
    WAITN(6); BAR();
    compute(0);
    BAR();

    // q3: issue (k+1,q0)->buf0
    if (k + 1 < KK) {
      stageB(0, tb + 32768);
      stageA(0, 0, nr);
      WAITN(6);
    } else {
      WAITN(0);
    }
    BAR();
    compute(1);
    BAR();

#pragma unroll
    for (int i = 0; i < 4; ++i) rr[i] = nr[i];
  }

  // --- epilogue: C/D layout col=lane&15, row=(lane>>4)*4+q ---------------
  float bv[4];
#pragma unroll
  for (int n = 0; n < 4; ++n) bv[n] = bias[wc * 64 + n * 16 + lr];
  const int rbase = row0 + wr * 128 + (l >> 4) * 4;
#pragma unroll
  for (int m = 0; m < 8; ++m)
#pragma unroll
    for (int n = 0; n < 4; ++n)
#pragma unroll
      for (int q = 0; q < 4; ++q)
        out[(size_t)(rbase + m * 16 + q) * CC + wc * 64 + n * 16 + lr] =
            acc[m][n][q] + bv[n];
}

extern "C" void kernel_launch(void* const* d_in, const int* in_sizes, int n_in,
                              void* d_out, int out_size, void* d_ws,
                              size_t ws_size, hipStream_t stream) {
  const float* x = (const float*)d_in[0];
  const float* w = (const float*)d_in[1];
  const float* b = (const float*)d_in[2];
  const int* neigh = (const int*)d_in[3];
  __hip_bfloat16* ws = (__hip_bfloat16*)d_ws;
  float* out = (float*)d_out;

  hipLaunchKernelGGL(prep_kernel, dim3(512), dim3(256), 0, stream, x, w, ws);
  hipLaunchKernelGGL(upconv_kernel, dim3(N_CHILD / BM), dim3(256), 0, stream,
                     neigh, ws, b, out);
}